// Round 2
// baseline (566.288 us; speedup 1.0000x reference)
//
#include <hip/hip_runtime.h>
#include <math.h>

#define BSZ 32
#define NA 3
#define NC 80
#define HH 64
#define WW 64
#define NT 50
#define NCH (NA*(5+NC))   // 255

constexpr int NCELL = BSZ*NA*HH*WW;   // 393216
constexpr float EPSf = 1e-12f;
constexpr float IGNORE_THR_C = 0.5f;

__device__ __forceinline__ float sigm(float x) { return 1.0f / (1.0f + expf(-x)); }

// ---------------- kernel 1: build target maps ----------------
__global__ void k_targets(const float* __restrict__ inp, const float* __restrict__ tgt,
                          unsigned char* __restrict__ mask_b, unsigned char* __restrict__ noobj_b,
                          float* __restrict__ txa, float* __restrict__ tya,
                          float* __restrict__ twa, float* __restrict__ tha,
                          float* __restrict__ gwa, unsigned int* __restrict__ clsbits)
{
    int b = blockIdx.x * blockDim.x + threadIdx.x;
    if (b >= BSZ) return;
    const float aw[3] = {1.25f, 2.0f, 4.125f};   // ANCHORS / stride(=8)
    const float ah[3] = {1.625f, 3.75f, 2.875f};

    for (int t = 0; t < NT; ++t) {
        const float* tg = tgt + (size_t)(b*NT + t)*5;
        float c0 = tg[0], c1 = tg[1], c2 = tg[2], c3 = tg[3], c4 = tg[4];
        if (!((c0 + c1 + c2 + c3 + c4) > 0.0f)) continue;   // valid gate

        float gx = c1 * WW, gy = c2 * HH, gw = c3 * WW, gh = c4 * HH;
        int gi = min(max((int)gx, 0), WW-1);
        int gj = min(max((int)gy, 0), HH-1);

        // anchor-shape IoU -> best_n (first max wins, like jnp.argmax)
        int best = 0; float bestiou = -1.0f;
        for (int a = 0; a < 3; ++a) {
            float inter = fminf(gw, aw[a]) * fminf(gh, ah[a]);
            float iou = inter / (gw*gh + aw[a]*ah[a] - inter + 1e-16f);
            if (iou > bestiou) { bestiou = iou; best = a; }
        }

        // pred_iou per anchor at (gj,gi): clear noobj where > thr
        for (int a = 0; a < 3; ++a) {
            size_t base = (((size_t)b*NCH + a*(5+NC))*HH + gj)*WW + gi;
            float px = sigm(inp[base + 0*(size_t)HH*WW]) + (float)gi;
            float py = sigm(inp[base + 1*(size_t)HH*WW]) + (float)gj;
            float pw = expf(inp[base + 2*(size_t)HH*WW]) * aw[a];
            float ph = expf(inp[base + 3*(size_t)HH*WW]) * ah[a];

            float b1x1 = gx - gw*0.5f, b1x2 = gx + gw*0.5f;
            float b1y1 = gy - gh*0.5f, b1y2 = gy + gh*0.5f;
            float b2x1 = px - pw*0.5f, b2x2 = px + pw*0.5f;
            float b2y1 = py - ph*0.5f, b2y2 = py + ph*0.5f;
            float iw = fmaxf(fminf(b1x2,b2x2) - fmaxf(b1x1,b2x1), 0.0f);
            float ih = fmaxf(fminf(b1y2,b2y2) - fmaxf(b1y1,b2y1), 0.0f);
            float inter = iw*ih;
            float a1 = (b1x2-b1x1)*(b1y2-b1y1);
            float a2 = (b2x2-b2x1)*(b2y2-b2y1);
            float piou = inter / (a1 + a2 - inter + 1e-16f);
            if (piou > IGNORE_THR_C) {
                int cell = ((b*NA + a)*HH + gj)*WW + gi;
                noobj_b[cell] = 0;
            }
        }

        // mask + regression targets at (b, best, gj, gi) — serial per b => last-writer-wins in t order
        int cell = ((b*NA + best)*HH + gj)*WW + gi;
        if (mask_b[cell] == 0) {
            mask_b[cell] = 1;
            clsbits[cell*3+0] = 0; clsbits[cell*3+1] = 0; clsbits[cell*3+2] = 0;
        }
        int ci = min(max((int)c0, 0), NC-1);
        clsbits[cell*3 + (ci >> 5)] |= (1u << (ci & 31));
        txa[cell] = gx - (float)gi;
        tya[cell] = gy - (float)gj;
        twa[cell] = logf(gw / aw[best] + 1e-16f);
        tha[cell] = logf(gh / ah[best] + 1e-16f);
        gwa[cell] = sigm(gw) * sigm(gh);
    }
}

// ---------------- kernel 2: per-cell loss terms + reduction ----------------
// sums: [0]=x [1]=y [2]=w [3]=h [4]=conf_obj [5]=conf_noobj [6]=cls [7]=n_sel
__global__ __launch_bounds__(256) void k_loss(const float* __restrict__ inp,
                       const unsigned char* __restrict__ mask_b,
                       const unsigned char* __restrict__ noobj_b,
                       const float* __restrict__ txa, const float* __restrict__ tya,
                       const float* __restrict__ twa, const float* __restrict__ tha,
                       const float* __restrict__ gwa,
                       const unsigned int* __restrict__ clsbits,
                       double* __restrict__ sums)
{
    int n = blockIdx.x * blockDim.x + threadIdx.x;
    double s[8] = {0,0,0,0,0,0,0,0};

    if (n < NCELL) {
        int i = n & (WW-1);
        int j = (n >> 6) & (HH-1);
        int a = (n >> 12) % NA;
        int b = n / (NA*HH*WW);
        size_t base = (((size_t)b*NCH + a*(5+NC))*HH + j)*WW + i;
        const size_t PL = (size_t)HH*WW;

        float conf = sigm(inp[base + 4*PL]);
        const float CONST0 = -log1pf(-EPSf);   // unmasked-cell BCE term (~1e-12)

        int m = mask_b[n];
        if (m) {
            float x = sigm(inp[base + 0*PL]);
            float y = sigm(inp[base + 1*PL]);
            float w = inp[base + 2*PL];
            float h = inp[base + 3*PL];
            float tx = txa[n], ty = tya[n], tw = twa[n], th = tha[n];
            float gwxh = gwa[n];

            float px = fminf(fmaxf(x, EPSf), 1.0f - EPSf);
            s[0] = (double)(-( tx*logf(px) + (1.0f-tx)*log1pf(-px) ));
            float py = fminf(fmaxf(y, EPSf), 1.0f - EPSf);
            s[1] = (double)(-( ty*logf(py) + (1.0f-ty)*log1pf(-py) ));

            float temp = (2.0f - gwxh); temp = temp*temp;
            float dw = (w - tw) * temp;  s[2] = (double)dw * (double)dw;
            float dh = (h - th) * temp;  s[3] = (double)dh * (double)dh;

            float pcf = fminf(fmaxf(conf, EPSf), 1.0f - EPSf);
            s[4] = (double)(-logf(pcf));   // t=1 at mask cells

            unsigned int bb0 = clsbits[n*3+0], bb1 = clsbits[n*3+1], bb2 = clsbits[n*3+2];
            double sc = 0.0;
            for (int c = 0; c < NC; ++c) {
                float p = sigm(inp[base + (size_t)(5+c)*PL]);
                p = fminf(fmaxf(p, EPSf), 1.0f - EPSf);
                unsigned int word = (c < 32) ? bb0 : ((c < 64) ? bb1 : bb2);
                float tc = (float)((word >> (c & 31)) & 1u);
                sc += (double)(-( tc*logf(p) + (1.0f-tc)*log1pf(-p) ));
            }
            s[6] = sc;
            s[7] = 1.0;
        } else {
            s[0] = CONST0; s[1] = CONST0; s[4] = CONST0;
        }

        if (noobj_b[n]) {
            float pcf = fminf(fmaxf(conf, EPSf), 1.0f - EPSf);
            s[5] = (double)(-log1pf(-pcf));   // t=0
        } else {
            s[5] = CONST0;
        }
    }

    // wave (64-lane) butterfly reduce, then cross-wave via LDS
    #pragma unroll
    for (int k = 0; k < 8; ++k) {
        double v = s[k];
        for (int off = 32; off > 0; off >>= 1) v += __shfl_down(v, off, 64);
        s[k] = v;
    }
    __shared__ double sh[4][8];
    int lane = threadIdx.x & 63, wv = threadIdx.x >> 6;
    if (lane == 0) {
        #pragma unroll
        for (int k = 0; k < 8; ++k) sh[wv][k] = s[k];
    }
    __syncthreads();
    if (threadIdx.x == 0) {
        #pragma unroll
        for (int k = 0; k < 8; ++k) {
            double v = sh[0][k] + sh[1][k] + sh[2][k] + sh[3][k];
            atomicAdd(&sums[k], v);
        }
    }
}

// ---------------- kernel 3: finalize ----------------
__global__ void k_final(const double* __restrict__ sums, float* __restrict__ out)
{
    if (blockIdx.x != 0 || threadIdx.x != 0) return;
    double N = (double)NCELL;
    double lx = sums[0] / N;
    double ly = sums[1] / N;
    double lw = sums[2] / N;
    double lh = sums[3] / N;
    double lconf = sums[4] / N + 0.5 * (sums[5] / N);
    double lcls  = sums[6] / (sums[7] * NC + 1e-16);
    double loss = (lx + ly) * 2.5 + (lw + lh) * 2.5 + lconf * 1.0 + lcls * 1.0;
    out[0] = (float)loss;
    out[1] = (float)lx;
    out[2] = (float)ly;
    out[3] = (float)lw;
    out[4] = (float)lh;
    out[5] = (float)lconf;
    out[6] = (float)lcls;
}

extern "C" void kernel_launch(void* const* d_in, const int* in_sizes, int n_in,
                              void* d_out, int out_size, void* d_ws, size_t ws_size,
                              hipStream_t stream)
{
    const float* inp = (const float*)d_in[0];
    const float* tgt = (const float*)d_in[1];
    float* out = (float*)d_out;

    char* ws = (char*)d_ws;
    double* sums          = (double*)ws;                                  // 64 B
    unsigned char* mask_b = (unsigned char*)(ws + 64);                    // NCELL
    unsigned char* noobj_b= mask_b + NCELL;                               // NCELL
    float* txa  = (float*)(ws + 64 + 2*(size_t)NCELL);
    float* tya  = txa + NCELL;
    float* twa  = tya + NCELL;
    float* tha  = twa + NCELL;
    float* gwa  = tha + NCELL;
    unsigned int* clsbits = (unsigned int*)(gwa + NCELL);                 // 3*NCELL u32

    hipMemsetAsync(sums, 0, 64, stream);
    hipMemsetAsync(mask_b, 0, NCELL, stream);
    hipMemsetAsync(noobj_b, 1, NCELL, stream);

    k_targets<<<1, 64, 0, stream>>>(inp, tgt, mask_b, noobj_b, txa, tya, twa, tha, gwa, clsbits);

    int nblk = (NCELL + 255) / 256;   // 1536
    k_loss<<<nblk, 256, 0, stream>>>(inp, mask_b, noobj_b, txa, tya, twa, tha, gwa, clsbits, sums);

    k_final<<<1, 64, 0, stream>>>(sums, out);
}

// Round 4
// 244.389 us; speedup vs baseline: 2.3172x; 2.3172x over previous
//
#include <hip/hip_runtime.h>
#include <math.h>

#define BSZ 32
#define NA 3
#define NC 80
#define HH 64
#define WW 64
#define NT 50
#define NCH (NA*(5+NC))   // 255

constexpr int NCELL = BSZ*NA*HH*WW;   // 393216
constexpr float EPSf = 1e-12f;
constexpr float IGNORE_THR_C = 0.5f;
constexpr float CONST0 = 1e-12f;                 // -log1p(-EPS)
constexpr float CLAMPB = 27.631021115928547f;    // -log(EPS)

__device__ __forceinline__ float sigm(float x) { return 1.0f / (1.0f + __expf(-x)); }
// softplus(x) = log(1+e^x), numerically stable; equals -log1p(-clip(sigm(x))) up to clamp
__device__ __forceinline__ float softplus(float x) {
    return fmaxf(x, 0.0f) + __logf(1.0f + __expf(-fabsf(x)));
}
__device__ __forceinline__ float bce_t0(float v) { return fminf(softplus(v),  CLAMPB); } // -log(1-p)
__device__ __forceinline__ float bce_t1(float v) { return fminf(softplus(-v), CLAMPB); } // -log(p)

// ---------------- kernel 1: build target maps (1 block per batch, 1 lane per target) ----------------
__global__ __launch_bounds__(64) void k_targets(const float* __restrict__ inp, const float* __restrict__ tgt,
                          unsigned char* __restrict__ mask_b, unsigned char* __restrict__ ignore_b,
                          float* __restrict__ txa, float* __restrict__ tya,
                          float* __restrict__ twa, float* __restrict__ tha,
                          float* __restrict__ gwa, unsigned int* __restrict__ clsbits)
{
    const int b = blockIdx.x;
    const int t = threadIdx.x;      // lane == target index
    const float aw[3] = {1.25f, 2.0f, 4.125f};   // ANCHORS / stride(=8)
    const float ah[3] = {1.625f, 3.75f, 2.875f};

    bool valid = false;
    int cell = -1, ci = 0, gi = 0, gj = 0, best = 0;
    float gx = 0, gy = 0, gw = 0, gh = 0;

    if (t < NT) {
        const float* tg = tgt + (size_t)(b*NT + t)*5;
        float c0 = tg[0], c1 = tg[1], c2 = tg[2], c3 = tg[3], c4 = tg[4];
        valid = (c0 + c1 + c2 + c3 + c4) > 0.0f;
        if (valid) {
            gx = c1 * WW; gy = c2 * HH; gw = c3 * WW; gh = c4 * HH;
            gi = min(max((int)gx, 0), WW-1);
            gj = min(max((int)gy, 0), HH-1);
            float bestiou = -1.0f;
            #pragma unroll
            for (int a = 0; a < 3; ++a) {     // first max wins, like jnp.argmax
                float inter = fminf(gw, aw[a]) * fminf(gh, ah[a]);
                float iou = inter / (gw*gh + aw[a]*ah[a] - inter + 1e-16f);
                if (iou > bestiou) { bestiou = iou; best = a; }
            }
            cell = ((b*NA + best)*HH + gj)*WW + gi;
            ci = min(max((int)c0, 0), NC-1);
        }
    }

    // pred-IoU ignore clearing: races benign (all writers store 1)
    if (valid) {
        #pragma unroll
        for (int a = 0; a < 3; ++a) {
            size_t base = (((size_t)b*NCH + a*(5+NC))*HH + gj)*WW + gi;
            const size_t PL = (size_t)HH*WW;
            float px = sigm(inp[base + 0*PL]) + (float)gi;
            float py = sigm(inp[base + 1*PL]) + (float)gj;
            float pw = __expf(inp[base + 2*PL]) * aw[a];
            float ph = __expf(inp[base + 3*PL]) * ah[a];

            float b1x1 = gx - gw*0.5f, b1x2 = gx + gw*0.5f;
            float b1y1 = gy - gh*0.5f, b1y2 = gy + gh*0.5f;
            float b2x1 = px - pw*0.5f, b2x2 = px + pw*0.5f;
            float b2y1 = py - ph*0.5f, b2y2 = py + ph*0.5f;
            float iw = fmaxf(fminf(b1x2,b2x2) - fmaxf(b1x1,b2x1), 0.0f);
            float ih = fmaxf(fminf(b1y2,b2y2) - fmaxf(b1y1,b2y1), 0.0f);
            float inter = iw*ih;
            float a1 = (b1x2-b1x1)*(b1y2-b1y1);
            float a2 = (b2x2-b2x1)*(b2y2-b2y1);
            float piou = inter / (a1 + a2 - inter + 1e-16f);
            if (piou > IGNORE_THR_C) {
                ignore_b[((b*NA + a)*HH + gj)*WW + gi] = 1;
            }
        }
    }

    // winner = last valid t per cell (matches serial last-writer-wins);
    // class bits = union over all valid same-cell targets. All via wave shfl — no atomics.
    bool winner = valid;
    unsigned int b0 = 0, b1 = 0, b2 = 0;
    for (int u = 0; u < NT; ++u) {
        int cu = __shfl(cell, u, 64);
        int vu = __shfl((int)valid, u, 64);
        int cu_ci = __shfl(ci, u, 64);
        if (vu && cu == cell) {
            if (u > t) winner = false;
            if (cu_ci < 32)      b0 |= 1u << cu_ci;
            else if (cu_ci < 64) b1 |= 1u << (cu_ci - 32);
            else                 b2 |= 1u << (cu_ci - 64);
        }
    }

    if (winner) {
        mask_b[cell] = 1;
        clsbits[cell*3+0] = b0;
        clsbits[cell*3+1] = b1;
        clsbits[cell*3+2] = b2;
        txa[cell] = gx - (float)gi;
        tya[cell] = gy - (float)gj;
        twa[cell] = logf(gw / aw[best] + 1e-16f);
        tha[cell] = logf(gh / ah[best] + 1e-16f);
        gwa[cell] = sigm(gw) * sigm(gh);
    }
}

// ---------------- kernel 2: per-cell loss terms + reduction (4 cells/thread) ----------------
// sums: [0]=x [1]=y [2]=w [3]=h [4]=conf_obj [5]=conf_noobj [6]=cls [7]=n_sel
__global__ __launch_bounds__(256) void k_loss(const float* __restrict__ inp,
                       const unsigned char* __restrict__ mask_b,
                       const unsigned char* __restrict__ ignore_b,
                       const float* __restrict__ txa, const float* __restrict__ tya,
                       const float* __restrict__ twa, const float* __restrict__ tha,
                       const float* __restrict__ gwa,
                       const unsigned int* __restrict__ clsbits,
                       double* __restrict__ sums)
{
    const int tid = blockIdx.x * blockDim.x + threadIdx.x;   // [0, NCELL/4)
    const int n0 = tid * 4;
    float s[8] = {0,0,0,0,0,0,0,0};

    {
        int i0 = n0 & (WW-1);
        int j  = (n0 >> 6) & (HH-1);
        int a  = (n0 >> 12) % NA;
        int b  = n0 / (NA*HH*WW);
        size_t base = (((size_t)b*NCH + a*(5+NC))*HH + j)*WW + i0;
        const size_t PL = (size_t)HH*WW;

        float4 conf4 = *reinterpret_cast<const float4*>(inp + base + 4*PL);
        unsigned int m4  = *reinterpret_cast<const unsigned int*>(mask_b + n0);
        unsigned int ig4 = *reinterpret_cast<const unsigned int*>(ignore_b + n0);
        const float cv[4] = {conf4.x, conf4.y, conf4.z, conf4.w};

        #pragma unroll
        for (int e = 0; e < 4; ++e) {
            float v = cv[e];
            bool m  = ((m4  >> (8*e)) & 0xff) != 0;
            bool ig = ((ig4 >> (8*e)) & 0xff) != 0;

            s[5] += ig ? CONST0 : bce_t0(v);          // 0.5*bce(conf*noobj, 0) numerator

            if (m) {
                int n = n0 + e;
                size_t be = base + e;
                float xv = inp[be + 0*PL];
                float yv = inp[be + 1*PL];
                float w  = inp[be + 2*PL];
                float h  = inp[be + 3*PL];
                float tx = txa[n], ty = tya[n], tw = twa[n], th = tha[n];
                float gwxh = gwa[n];

                s[0] += tx*bce_t1(xv) + (1.0f - tx)*bce_t0(xv);
                s[1] += ty*bce_t1(yv) + (1.0f - ty)*bce_t0(yv);

                float temp = (2.0f - gwxh); temp = temp*temp;
                float dw = (w - tw) * temp;  s[2] += dw*dw;
                float dh = (h - th) * temp;  s[3] += dh*dh;

                s[4] += bce_t1(v);                     // t=1 at mask cells

                unsigned int bb0 = clsbits[n*3+0], bb1 = clsbits[n*3+1], bb2 = clsbits[n*3+2];
                float sc = 0.0f;
                for (int c = 0; c < NC; ++c) {
                    float p = inp[be + (size_t)(5+c)*PL];
                    unsigned int word = (c < 32) ? bb0 : ((c < 64) ? bb1 : bb2);
                    bool tc = (word >> (c & 31)) & 1u;
                    sc += tc ? bce_t1(p) : bce_t0(p);
                }
                s[6] += sc;
                s[7] += 1.0f;
            } else {
                s[0] += CONST0; s[1] += CONST0; s[4] += CONST0;
            }
        }
    }

    // wave butterfly reduce (float), then cross-wave via LDS, one f64 atomic set per block
    #pragma unroll
    for (int k = 0; k < 8; ++k) {
        float v = s[k];
        for (int off = 32; off > 0; off >>= 1) v += __shfl_down(v, off, 64);
        s[k] = v;
    }
    __shared__ float sh[4][8];
    int lane = threadIdx.x & 63, wv = threadIdx.x >> 6;
    if (lane == 0) {
        #pragma unroll
        for (int k = 0; k < 8; ++k) sh[wv][k] = s[k];
    }
    __syncthreads();
    if (threadIdx.x == 0) {
        #pragma unroll
        for (int k = 0; k < 8; ++k) {
            double v = (double)sh[0][k] + (double)sh[1][k] + (double)sh[2][k] + (double)sh[3][k];
            atomicAdd(&sums[k], v);
        }
    }
}

// ---------------- kernel 3: finalize ----------------
__global__ void k_final(const double* __restrict__ sums, float* __restrict__ out)
{
    if (blockIdx.x != 0 || threadIdx.x != 0) return;
    double N = (double)NCELL;
    double lx = sums[0] / N;
    double ly = sums[1] / N;
    double lw = sums[2] / N;
    double lh = sums[3] / N;
    double lconf = sums[4] / N + 0.5 * (sums[5] / N);
    double lcls  = sums[6] / (sums[7] * NC + 1e-16);
    double loss = (lx + ly) * 2.5 + (lw + lh) * 2.5 + lconf * 1.0 + lcls * 1.0;
    out[0] = (float)loss;
    out[1] = (float)lx;
    out[2] = (float)ly;
    out[3] = (float)lw;
    out[4] = (float)lh;
    out[5] = (float)lconf;
    out[6] = (float)lcls;
}

extern "C" void kernel_launch(void* const* d_in, const int* in_sizes, int n_in,
                              void* d_out, int out_size, void* d_ws, size_t ws_size,
                              hipStream_t stream)
{
    const float* inp = (const float*)d_in[0];
    const float* tgt = (const float*)d_in[1];
    float* out = (float*)d_out;

    // layout: [sums 64B][mask NCELL][ignore NCELL] — zeroed in ONE memset;
    // [tx..gwa 5×NCELL f32][clsbits 3×NCELL u32] — written-before-read (only where mask==1)
    char* ws = (char*)d_ws;
    double* sums           = (double*)ws;
    unsigned char* mask_b  = (unsigned char*)(ws + 64);
    unsigned char* ignore_b= mask_b + NCELL;
    float* txa  = (float*)(ws + 64 + 2*(size_t)NCELL);
    float* tya  = txa + NCELL;
    float* twa  = tya + NCELL;
    float* tha  = twa + NCELL;
    float* gwa  = tha + NCELL;
    unsigned int* clsbits = (unsigned int*)(gwa + NCELL);

    hipMemsetAsync(ws, 0, 64 + 2*(size_t)NCELL, stream);

    k_targets<<<BSZ, 64, 0, stream>>>(inp, tgt, mask_b, ignore_b, txa, tya, twa, tha, gwa, clsbits);

    int nthreads = NCELL / 4;                    // 98304
    k_loss<<<nthreads/256, 256, 0, stream>>>(inp, mask_b, ignore_b, txa, tya, twa, tha, gwa, clsbits, sums);

    k_final<<<1, 64, 0, stream>>>(sums, out);
}